// Round 1
// baseline (105.769 us; speedup 1.0000x reference)
//
#include <hip/hip_runtime.h>

#define NTH   200      // number of thresholds
#define NBINS 201      // count values 0..200
#define HSIZE (2 * NBINS)  // interleaved [neg, pos] per bin = 402 u32

// Kernel 1: histogram of "how many thresholds does p exceed", split by label.
// bin = 2*count + (label != 0)
__global__ void __launch_bounds__(256)
auroc_hist_kernel(const float* __restrict__ preds,
                  const int*   __restrict__ labels,
                  const float* __restrict__ thresholds,
                  unsigned int* __restrict__ g_hist,
                  int n) {
    __shared__ float        s_th[NTH];
    __shared__ unsigned int s_hist[HSIZE];

    const int t = threadIdx.x;
    for (int i = t; i < HSIZE; i += blockDim.x) s_hist[i] = 0u;
    for (int i = t; i < NTH;   i += blockDim.x) s_th[i]   = thresholds[i];
    __syncthreads();

    const int gid    = blockIdx.x * blockDim.x + t;
    const int stride = gridDim.x * blockDim.x;
    const int n4     = n >> 2;

    const float4* p4 = (const float4*)preds;
    const int4*   l4 = (const int4*)labels;

    for (int i = gid; i < n4; i += stride) {
        float4 p = p4[i];
        int4   l = l4[i];
        float  pv[4] = {p.x, p.y, p.z, p.w};
        int    lv[4] = {l.x, l.y, l.z, l.w};
#pragma unroll
        for (int j = 0; j < 4; ++j) {
            float pp = pv[j];
            // lower_bound: smallest idx with s_th[idx] >= pp; count = idx in [0,200]
            int g = (int)(pp * 199.0f);
            g = g < 0 ? 0 : (g > 200 ? 200 : g);
            while (g < NTH && s_th[g] < pp)      ++g;   // at most ~1 iter
            while (g > 0   && s_th[g - 1] >= pp) --g;   // at most ~1 iter
            int bin = (g << 1) | (lv[j] != 0 ? 1 : 0);
            atomicAdd(&s_hist[bin], 1u);
        }
    }
    // scalar tail (N=4M is divisible by 4, but stay general)
    for (int i = (n4 << 2) + gid; i < n; i += stride) {
        float pp = preds[i];
        int g = (int)(pp * 199.0f);
        g = g < 0 ? 0 : (g > 200 ? 200 : g);
        while (g < NTH && s_th[g] < pp)      ++g;
        while (g > 0   && s_th[g - 1] >= pp) --g;
        int bin = (g << 1) | (labels[i] != 0 ? 1 : 0);
        atomicAdd(&s_hist[bin], 1u);
    }
    __syncthreads();

    for (int i = t; i < HSIZE; i += blockDim.x) {
        unsigned int v = s_hist[i];
        if (v) atomicAdd(&g_hist[i], v);
    }
}

// Kernel 2: suffix sums -> (FPR, TPR) per threshold -> trapezoidal AUC.
__global__ void __launch_bounds__(256)
auroc_finish_kernel(const unsigned int* __restrict__ g_hist,
                    float* __restrict__ out) {
    __shared__ unsigned int s_h[HSIZE];
    __shared__ float s_x[NTH];
    __shared__ float s_y[NTH];
    __shared__ unsigned int s_sufp[NBINS + 1];
    __shared__ unsigned int s_sufn[NBINS + 1];

    const int t = threadIdx.x;
    for (int i = t; i < HSIZE; i += blockDim.x) s_h[i] = g_hist[i];
    if (t == 0) { s_sufp[NBINS] = 0u; s_sufn[NBINS] = 0u; }
    __syncthreads();

    // suffix sums over bins: suf[k] = sum_{j>=k} hist[j]
    if (t < NBINS) {
        unsigned int sp = 0u, sn = 0u;
        for (int k = t; k < NBINS; ++k) {
            sn += s_h[2 * k];
            sp += s_h[2 * k + 1];
        }
        s_sufp[t] = sp;
        s_sufn[t] = sn;
    }
    __syncthreads();

    const float P  = (float)s_sufp[0];  // total positives
    const float Nn = (float)s_sufn[0];  // total negatives
    const float EPS = 1e-6f;

    if (t < NTH) {
        float tp = (float)s_sufp[t + 1];  // count > t  <=>  p > th[t]
        float fp = (float)s_sufn[t + 1];
        float fn = P - tp;
        float tn = Nn - fp;
        s_y[t] = (tp + EPS) / (tp + fn + EPS);  // TPR
        s_x[t] = fp / (fp + tn + EPS);          // FPR
    }
    __syncthreads();

    if (t == 0) {
        double auc = 0.0;
        for (int i = 0; i < NTH - 1; ++i) {
            auc += (double)((s_x[i] - s_x[i + 1]) * (s_y[i] + s_y[i + 1]) * 0.5f);
        }
        out[0] = (float)auc;
    }
}

extern "C" void kernel_launch(void* const* d_in, const int* in_sizes, int n_in,
                              void* d_out, int out_size, void* d_ws, size_t ws_size,
                              hipStream_t stream) {
    const float* preds      = (const float*)d_in[0];
    const int*   labels     = (const int*)d_in[1];
    const float* thresholds = (const float*)d_in[2];
    float*       out        = (float*)d_out;
    unsigned int* g_hist    = (unsigned int*)d_ws;

    const int n = in_sizes[0];

    // ws is re-poisoned to 0xAA before every timed launch — zero it.
    hipMemsetAsync(g_hist, 0, HSIZE * sizeof(unsigned int), stream);

    auroc_hist_kernel<<<512, 256, 0, stream>>>(preds, labels, thresholds, g_hist, n);
    auroc_finish_kernel<<<1, 256, 0, stream>>>(g_hist, out);
}